// Round 1
// baseline (19.818 us; speedup 1.0000x reference)
//
#include <hip/hip_runtime.h>

// Kernel 1: per-row projections.
// proj_i[r][c] = sum_k embeds[r][k]      * weight[c][k]        (c = 0,1; k < 256)
// proj_j[r][c] = sum_k embeds_temp[r][k] * weight[c][256 + k]
// One 64-lane wave per row; lane l owns elements 4l..4l+3 (float4).
__global__ void proj_kernel(const float* __restrict__ embeds,
                            const float* __restrict__ embeds_temp,
                            const float* __restrict__ weight,   // (2, 512) row-major
                            float* __restrict__ proj_i,         // (n, 2)
                            float* __restrict__ proj_j,         // (n, 2)
                            int n) {
    const int wave = (int)((blockIdx.x * blockDim.x + threadIdx.x) >> 6);
    const int lane = (int)(threadIdx.x & 63);
    if (wave >= n) return;

    const size_t row_off = (size_t)wave * 256 + (size_t)lane * 4;
    const float4 e  = *(const float4*)(embeds      + row_off);
    const float4 et = *(const float4*)(embeds_temp + row_off);

    // weight[0][0:256]=w_i0, weight[0][256:512]=w_j0,
    // weight[1][0:256]=w_i1, weight[1][256:512]=w_j1
    const float4 wi0 = *(const float4*)(weight +   0 + lane * 4);
    const float4 wj0 = *(const float4*)(weight + 256 + lane * 4);
    const float4 wi1 = *(const float4*)(weight + 512 + lane * 4);
    const float4 wj1 = *(const float4*)(weight + 768 + lane * 4);

    float pi0 = e.x * wi0.x + e.y * wi0.y + e.z * wi0.z + e.w * wi0.w;
    float pi1 = e.x * wi1.x + e.y * wi1.y + e.z * wi1.z + e.w * wi1.w;
    float pj0 = et.x * wj0.x + et.y * wj0.y + et.z * wj0.z + et.w * wj0.w;
    float pj1 = et.x * wj1.x + et.y * wj1.y + et.z * wj1.z + et.w * wj1.w;

    // 64-lane butterfly reduction (wave = 64 on CDNA4)
    #pragma unroll
    for (int m = 32; m >= 1; m >>= 1) {
        pi0 += __shfl_xor(pi0, m);
        pi1 += __shfl_xor(pi1, m);
        pj0 += __shfl_xor(pj0, m);
        pj1 += __shfl_xor(pj1, m);
    }

    if (lane == 0) {
        proj_i[2 * (size_t)wave + 0] = pi0;
        proj_i[2 * (size_t)wave + 1] = pi1;
        proj_j[2 * (size_t)wave + 0] = pj0;
        proj_j[2 * (size_t)wave + 1] = pj1;
    }
}

// Kernel 2: pair gather. out[p][c] = proj_i[idx_i[p]][c] + proj_j[idx_j[p]][c] + bias[c]
__global__ void gather_kernel(const float* __restrict__ proj_i,
                              const float* __restrict__ proj_j,
                              const int* __restrict__ idx_i,
                              const int* __restrict__ idx_j,
                              const float* __restrict__ bias,
                              float* __restrict__ out,
                              int npairs) {
    const int p = (int)(blockIdx.x * blockDim.x + threadIdx.x);
    if (p >= npairs) return;
    const int i = idx_i[p];
    const int j = idx_j[p];
    const float2 a = *(const float2*)(proj_i + 2 * (size_t)i);
    const float2 b = *(const float2*)(proj_j + 2 * (size_t)j);
    float2 o;
    o.x = a.x + b.x + bias[0];
    o.y = a.y + b.y + bias[1];
    *(float2*)(out + 2 * (size_t)p) = o;
}

extern "C" void kernel_launch(void* const* d_in, const int* in_sizes, int n_in,
                              void* d_out, int out_size, void* d_ws, size_t ws_size,
                              hipStream_t stream) {
    const float* embeds      = (const float*)d_in[0];
    const float* embeds_temp = (const float*)d_in[1];
    const float* weight      = (const float*)d_in[2];
    const float* bias        = (const float*)d_in[3];
    const int*   idx_i       = (const int*)d_in[4];
    const int*   idx_j       = (const int*)d_in[5];
    float* out = (float*)d_out;

    const int n      = in_sizes[0] / 256;   // rows
    const int npairs = in_sizes[4];         // pairs

    float* proj_i = (float*)d_ws;
    float* proj_j = proj_i + (size_t)n * 2;

    // Kernel 1: one wave per row, 4 waves per 256-thread block.
    const int rows_per_block = 4;
    dim3 grid1((n + rows_per_block - 1) / rows_per_block);
    proj_kernel<<<grid1, 256, 0, stream>>>(embeds, embeds_temp, weight,
                                           proj_i, proj_j, n);

    // Kernel 2: one thread per pair.
    dim3 grid2((npairs + 255) / 256);
    gather_kernel<<<grid2, 256, 0, stream>>>(proj_i, proj_j, idx_i, idx_j,
                                             bias, out, npairs);
}